// Round 14
// baseline (140.071 us; speedup 1.0000x reference)
//
#include <hip/hip_runtime.h>

typedef unsigned short u16;
typedef unsigned int   u32;
typedef __bf16 bf16x8 __attribute__((ext_vector_type(8)));
typedef __bf16 bf16x2 __attribute__((ext_vector_type(2)));
typedef float  f32x4  __attribute__((ext_vector_type(4)));

#define B_     2
#define N_     2048
#define DIM_   1024
#define HEADS_ 16
#define DH_    64
#define BH_    (B_*HEADS_)   // 32
#define ROWS_  (B_*N_)       // 4096

__device__ __forceinline__ u16 f2b(float f) {
  union { __bf16 h; u16 u; } v; v.h = (__bf16)f; return v.u;
}
__device__ __forceinline__ u32 pkb(float a, float b) {
  bf16x2 t; t[0] = (__bf16)a; t[1] = (__bf16)b;
  union { bf16x2 v; u32 u; } c; c.v = t; return c.u;
}
__device__ __forceinline__ float b2f(u16 h) {
  union { u32 u; float f; } v; v.u = ((u32)h) << 16;
  return v.f;
}
__device__ __forceinline__ void gload16(const void* g, void* l) {
  __builtin_amdgcn_global_load_lds(
      (const __attribute__((address_space(1))) void*)g,
      (__attribute__((address_space(3))) void*)l, 16, 0, 0);
}
__device__ __forceinline__ f32x4 mfma16(bf16x8 a, bf16x8 b, f32x4 c) {
  return __builtin_amdgcn_mfma_f32_16x16x32_bf16(a, b, c, 0, 0, 0);
}

// ---------------- LayerNorm -> bf16 ----------------
__global__ __launch_bounds__(256) void ln_kernel(const float* __restrict__ x,
    const float* __restrict__ lw, const float* __restrict__ lb,
    u16* __restrict__ xn) {
  int r = blockIdx.x, t = threadIdx.x;
  const float4* xr = (const float4*)(x + (size_t)r * DIM_);
  float4 v = xr[t];
  float s  = v.x + v.y + v.z + v.w;
  float s2 = v.x*v.x + v.y*v.y + v.z*v.z + v.w*v.w;
  #pragma unroll
  for (int off = 32; off >= 1; off >>= 1) {
    s  += __shfl_down(s, off);
    s2 += __shfl_down(s2, off);
  }
  __shared__ float ps[4], ps2[4], bc[2];
  int w = t >> 6, lane = t & 63;
  if (lane == 0) { ps[w] = s; ps2[w] = s2; }
  __syncthreads();
  if (t == 0) {
    float S = ps[0]+ps[1]+ps[2]+ps[3], S2 = ps2[0]+ps2[1]+ps2[2]+ps2[3];
    float mu = S * (1.0f/DIM_);
    float var = S2 * (1.0f/DIM_) - mu*mu;
    bc[0] = mu; bc[1] = rsqrtf(var + 1e-5f);
  }
  __syncthreads();
  float mu = bc[0], rs = bc[1];
  float4 wv = ((const float4*)lw)[t];
  float4 bv = ((const float4*)lb)[t];
  u32 lo = pkb((v.x-mu)*rs*wv.x + bv.x, (v.y-mu)*rs*wv.y + bv.y);
  u32 hi = pkb((v.z-mu)*rs*wv.z + bv.z, (v.w-mu)*rs*wv.w + bv.w);
  ((uint2*)xn)[(size_t)r*256 + t] = make_uint2(lo, hi);
}

// ---------------- f32 (R x C) -> bf16 transposed (C x R) ----------------
__global__ __launch_bounds__(256) void transpose_f32_bf16(const float* __restrict__ in,
    u16* __restrict__ out, int R, int C) {
  __shared__ float tile[32][33];
  int tx = threadIdx.x & 31, ty = threadIdx.x >> 5;
  int c0 = blockIdx.x * 32, r0 = blockIdx.y * 32;
  #pragma unroll
  for (int i = 0; i < 4; i++)
    tile[ty + i*8][tx] = in[(size_t)(r0 + ty + i*8) * C + c0 + tx];
  __syncthreads();
  #pragma unroll
  for (int i = 0; i < 4; i++)
    out[(size_t)(c0 + ty + i*8) * R + r0 + tx] = f2b(tile[tx][ty + i*8]);
}

// ---------------- QKV GEMM: 256x256 tile, BK=64, double-buffered ----------
// 8 waves (2M x 4N), 512 threads, 128KB LDS, row-XOR-swizzled (T2).
// Per K-tile: 4 quadrant-phases x 16 MFMA, ONE __syncthreads at the boundary.
// Tile t+1 staged during tile t's first two phases (>=2-phase lead covers HBM
// latency; boundary syncthreads' implicit vmcnt(0) is then cheap).
// Epilogue: scatter q (bh,n,d), k (bh,n,d), v^T (bh,d,n).
__global__ __launch_bounds__(512, 2) void gemm256_qkv(
    const u16* __restrict__ A, const u16* __restrict__ Bt,
    u16* __restrict__ qo, u16* __restrict__ ko, u16* __restrict__ vo) {
  __shared__ __align__(16) char lds[131072];   // 2 x (A 32KB | B 32KB)
  const int K = 1024;
  int tid = threadIdx.x;
  int lane = tid & 63;
  int w = tid >> 6, wm = w >> 2, wn = w & 3;
  int l15 = lane & 15, g = lane >> 4;
  int lin = blockIdx.x;
  int nb = (lin & 7) * 24 + (lin >> 3);        // XCD swizzle (192 = 8*24)
  int bm = nb & 15, bn = nb >> 4;              // 16 x 12
  int srow = tid >> 3;                         // 0..63
  int ssoff = ((tid & 7) * 16) ^ ((srow & 7) << 4);
  const char* Ab = (const char*)A;
  const char* Bb = (const char*)Bt;
  const int swz = (l15 & 7) << 4;

  f32x4 acc[8][4];
  #pragma unroll
  for (int i = 0; i < 8; i++)
    #pragma unroll
    for (int j = 0; j < 4; j++)
      acc[i][j] = (f32x4){0.f, 0.f, 0.f, 0.f};

#define SA(t, buf) { _Pragma("unroll") for (int j = 0; j < 4; j++) \
    gload16(Ab + ((size_t)(bm*256 + j*64 + srow) * K + (size_t)(t)*64) * 2 + ssoff, \
            lds + (buf)*65536 + j*8192 + tid*16); }
#define SB(t, buf) { _Pragma("unroll") for (int j = 0; j < 4; j++) \
    gload16(Bb + ((size_t)(bn*256 + j*64 + srow) * K + (size_t)(t)*64) * 2 + ssoff, \
            lds + (buf)*65536 + 32768 + j*8192 + tid*16); }
#define RDA(qm) { _Pragma("unroll") for (int mt = 0; mt < 4; mt++) { \
    const char* ar = lA + (wm*128 + ((qm)*4 + mt)*16 + l15)*128; \
    af[mt][0] = *(const bf16x8*)(ar + ((g*16) ^ swz)); \
    af[mt][1] = *(const bf16x8*)(ar + ((64 + g*16) ^ swz)); } }
#define RDB(qn) { _Pragma("unroll") for (int nt = 0; nt < 2; nt++) { \
    const char* br = lB + (wn*64 + ((qn)*2 + nt)*16 + l15)*128; \
    bfr[nt][0] = *(const bf16x8*)(br + ((g*16) ^ swz)); \
    bfr[nt][1] = *(const bf16x8*)(br + ((64 + g*16) ^ swz)); } }
#define MM(qm, qn) { __builtin_amdgcn_s_setprio(1); \
    _Pragma("unroll") for (int mt = 0; mt < 4; mt++) \
    _Pragma("unroll") for (int nt = 0; nt < 2; nt++) { \
      f32x4 c = acc[(qm)*4 + mt][(qn)*2 + nt]; \
      c = mfma16(af[mt][0], bfr[nt][0], c); \
      c = mfma16(af[mt][1], bfr[nt][1], c); \
      acc[(qm)*4 + mt][(qn)*2 + nt] = c; } \
    __builtin_amdgcn_s_setprio(0); }

  // prologue: stage tiles 0 and 1
  SA(0, 0) SB(0, 0) SA(1, 1) SB(1, 1)
  __syncthreads();

  #pragma unroll 1
  for (int t = 0; t < 16; ++t) {
    const char* lA = lds + (t & 1)*65536;
    const char* lB = lA + 32768;
    int nbuf = (t + 1) & 1;
    bf16x8 af[4][2], bfr[2][2];
    // phase 0: (qm0, qn0) + stage A(t+1)
    RDA(0) RDB(0)
    if (t >= 1 && t < 15) SA(t + 1, nbuf)
    MM(0, 0)
    // phase 1: (qm0, qn1) + stage B(t+1)
    RDB(1)
    if (t >= 1 && t < 15) SB(t + 1, nbuf)
    MM(0, 1)
    // phase 2: (qm1, qn0)
    RDA(1) RDB(0)
    MM(1, 0)
    // phase 3: (qm1, qn1)
    RDB(1)
    MM(1, 1)
    if (t < 15) __syncthreads();
  }
#undef SA
#undef SB
#undef RDA
#undef RDB
#undef MM

  // epilogue: scatter
  #pragma unroll
  for (int mi = 0; mi < 8; mi++) {
    #pragma unroll
    for (int ni = 0; ni < 4; ni++) {
      #pragma unroll
      for (int reg = 0; reg < 4; reg++) {
        int rr = bm*256 + wm*128 + mi*16 + g*4 + reg;
        int cc = bn*256 + wn*64 + ni*16 + l15;
        float val = acc[mi][ni][reg];
        int which = cc >> 10, inner = cc & 1023;
        int h = inner >> 6, dd = inner & 63;
        int b = rr >> 11, np = rr & 2047;
        int bh = b*HEADS_ + h;
        if (which == 0)      qo[((size_t)(bh*2048 + np))*64 + dd] = f2b(val);
        else if (which == 1) ko[((size_t)(bh*2048 + np))*64 + dd] = f2b(val);
        else                 vo[((size_t)(bh*64 + dd))*2048 + np] = f2b(val);
      }
    }
  }
}

// ---------------- GEMM: A (M x K bf16) x Bt (N x K bf16) ----------------
// Measured-best structure: single-buffer LDS + syncthreads, BK=32, 2-D grid.
// MODE 1: out[r*N+c] = acc + bias[c]  (f32)
template<int MODE>
__global__ __launch_bounds__(256) void gemm_bt(
    const u16* __restrict__ A, const u16* __restrict__ Bt, int N, int K,
    u16* __restrict__ qo, u16* __restrict__ ko, u16* __restrict__ vo,
    const float* __restrict__ bias, float* __restrict__ out) {
  __shared__ __align__(16) u16 lA[128*32];
  __shared__ __align__(16) u16 lB[128*32];
  int tid = threadIdx.x;
  int lane = tid & 63;
  int w = tid >> 6, wm = w >> 1, wn = w & 1;
  int l15 = lane & 15, g = lane >> 4;
  int bm = blockIdx.x, bn = blockIdx.y;
  const f32x4 z = {0.f, 0.f, 0.f, 0.f};
  f32x4 acc[4][4];
  #pragma unroll
  for (int i = 0; i < 4; i++)
    #pragma unroll
    for (int j = 0; j < 4; j++)
      acc[i][j] = z;
  const u16* ag = A  + (size_t)(bm*128 + (tid>>2)) * K + (tid&3)*8;
  const u16* bg = Bt + (size_t)(bn*128 + (tid>>2)) * K + (tid&3)*8;
  u16* la = lA + tid*8;
  u16* lb = lB + tid*8;
  for (int k0 = 0; k0 < K; k0 += 32) {
    gload16(ag + k0,                la);
    gload16(ag + (size_t)64*K + k0, la + 2048);
    gload16(bg + k0,                lb);
    gload16(bg + (size_t)64*K + k0, lb + 2048);
    __syncthreads();
    bf16x8 af[4], bfr[4];
    #pragma unroll
    for (int mt = 0; mt < 4; mt++)
      af[mt] = *(const bf16x8*)(lA + (wm*64 + mt*16 + l15)*32 + g*8);
    #pragma unroll
    for (int nt = 0; nt < 4; nt++)
      bfr[nt] = *(const bf16x8*)(lB + (wn*64 + nt*16 + l15)*32 + g*8);
    __builtin_amdgcn_s_setprio(1);
    #pragma unroll
    for (int mt = 0; mt < 4; mt++)
      #pragma unroll
      for (int nt = 0; nt < 4; nt++)
        acc[mt][nt] = mfma16(af[mt], bfr[nt], acc[mt][nt]);
    __builtin_amdgcn_s_setprio(0);
    __syncthreads();
  }
  #pragma unroll
  for (int mt = 0; mt < 4; mt++) {
    #pragma unroll
    for (int nt = 0; nt < 4; nt++) {
      #pragma unroll
      for (int reg = 0; reg < 4; reg++) {
        int rr = bm*128 + wm*64 + mt*16 + g*4 + reg;
        int cc = bn*128 + wn*64 + nt*16 + l15;
        float val = acc[mt][nt][reg];
        if (MODE == 0) {
          int which = cc >> 10, inner = cc & 1023;
          int h = inner >> 6, dd = inner & 63;
          int b = rr >> 11, np = rr & 2047;
          int bh = b*HEADS_ + h;
          if (which == 0)      qo[((size_t)(bh*2048 + np))*64 + dd] = f2b(val);
          else if (which == 1) ko[((size_t)(bh*2048 + np))*64 + dd] = f2b(val);
          else                 vo[((size_t)(bh*64 + dd))*2048 + np] = f2b(val);
        } else {
          out[(size_t)rr * N + cc] = val + bias[cc];
        }
      }
    }
  }
}

// ---------------- RoPE in-place on q,k (bh,n,64); coalesced, inline trig ----
// q additionally scaled by DH^-1/2 * log2(e)  (scores land in log2 domain)
__global__ __launch_bounds__(256) void rope_kernel(u16* q, u16* k) {
  int tid = blockIdx.x * 256 + threadIdx.x;   // 524288 = BH*N*8
  int row = tid >> 3, sub = tid & 7;
  int n = row & 2047;
  u32* qp = (u32*)(q + (size_t)row * 64 + sub * 8);
  u32* kp = (u32*)(k + (size_t)row * 64 + sub * 8);
  uint4 uq = *(uint4*)qp;
  uint4 uk = *(uint4*)kp;
  float c4[4], s4[4];
  #pragma unroll
  for (int j = 0; j < 4; j++) {
    int p = sub*4 + j;
    float freq = expf(-(2.0f * (float)p) * (9.210340371976184f / 64.0f));
    float ang = (float)n * freq;
    __sincosf(ang, &s4[j], &c4[j]);
  }
  const float qs = 0.125f * 1.4426950408889634f;
#define ROPE_Q(u, c, s) { \
    float e = b2f((u16)(u)), o = b2f((u16)((u) >> 16)); \
    (u) = pkb((e*(c) - o*(s))*qs, (o*(c) + e*(s))*qs); }
#define ROPE_K(u, c, s) { \
    float e = b2f((u16)(u)), o = b2f((u16)((u) >> 16)); \
    (u) = pkb(e*(c) - o*(s), o*(c) + e*(s)); }
  ROPE_Q(uq.x, c4[0], s4[0]) ROPE_Q(uq.y, c4[1], s4[1])
  ROPE_Q(uq.z, c4[2], s4[2]) ROPE_Q(uq.w, c4[3], s4[3])
  ROPE_K(uk.x, c4[0], s4[0]) ROPE_K(uk.y, c4[1], s4[1])
  ROPE_K(uk.z, c4[2], s4[2]) ROPE_K(uk.w, c4[3], s4[3])
#undef ROPE_Q
#undef ROPE_K
  *(uint4*)qp = uq;
  *(uint4*)kp = uk;
}

// ---------------- Flash attention (key-split wave pairs; R13, measured) -----
__global__ __launch_bounds__(512, 4) void flash_attn(
    const u16* __restrict__ qbf, const u16* __restrict__ kbf,
    const u16* __restrict__ vt, u16* __restrict__ aout) {
  __shared__ __align__(16) char smem[49152];      // 3x8KB K | 3x8KB V; reused
  char* lK = smem;            // lK[buf] at buf*8192
  char* lV = smem + 24576;    // lV[buf] at 24576 + buf*8192
  int tid = threadIdx.x;
  int w = tid >> 6, lane = tid & 63;
  int l15 = lane & 15, g = lane >> 4;
  int p = w & 3, rho = w >> 2;
  int lin = blockIdx.x;
  int nb = (lin & 7) * 64 + (lin >> 3);
  int bh = nb >> 4, qb = nb & 15;
  const f32x4 z = {0.f, 0.f, 0.f, 0.f};
  // Q B-fragments: q = p*32 + qt*16 + l15, d = dh*32 + g*8 .. +7
  const u16* qrow_base = qbf + ((size_t)bh*2048 + qb*128 + p*32) * 64;
  bf16x8 Qf[2][2];
  #pragma unroll
  for (int qt = 0; qt < 2; qt++)
    #pragma unroll
    for (int dh = 0; dh < 2; dh++)
      Qf[qt][dh] = *(const bf16x8*)(qrow_base + (qt*16 + l15)*64 + dh*32 + g*8);
  const char* kb = (const char*)(kbf + (size_t)bh * 2048 * 64);
  const char* vb = (const char*)(vt  + (size_t)bh * 64 * 2048);
  int srow = tid >> 3;                 // LDS row 0..63
  int soff = ((tid & 7) * 16) ^ ((srow & 7) << 4);   // inverse-swizzled source
  // 5-bit kappa within each 32-key half: key = half | (s3s2)<<3 | s4<<2 | s1s0
  int sl = srow & 31;
  int ksrc = (srow & 32) | (((sl >> 2) & 3) << 3) | (((sl >> 4) & 1) << 2) | (sl & 3);
  const int swz = (l15 & 7) << 4;      // row-XOR read swizzle

  float lp[2][2] = {{0.f, 0.f}, {0.f, 0.f}};   // [qt][kt] partial denominators
  f32x4 o[4][2];                               // [dt][qt] partial O^T
  #pragma unroll
  for (int i = 0; i < 4; i++)
    #pragma unroll
    for (int j = 0; j < 2; j++)
      o[i][j] = z;

#define STAGE(t, buf) { \
    gload16(kb + (size_t)((t)*64 + ksrc) * 128 + soff, lK + (buf)*8192 + (size_t)tid*16); \
    gload16(vb + (size_t)srow * 4096 + (t)*128 + soff, lV + (buf)*8192 + (size_t)tid*16); }

  STAGE(0, 0)
  STAGE(1, 1)
  asm volatile("s_waitcnt vmcnt(2)" ::: "memory");
  __builtin_amdgcn_s_barrier();

  int cur = 0, pfb = 2;
  #pragma unroll 1
  for (int t = 0; t < 32; ++t) {
    if (t < 30) STAGE(t + 2, pfb)
    const char* Kc = lK + cur*8192;
    const char* Vc = lV + cur*8192;
    // QK^T over this wave's 32-key half: st[kt][qt]
    f32x4 st[2][2];
    bf16x8 ka[2][2];
    #pragma unroll
    for (int kt = 0; kt < 2; kt++)
      #pragma unroll
      for (int dh = 0; dh < 2; dh++)
        ka[kt][dh] = *(const bf16x8*)(Kc + (rho*32 + kt*16 + l15)*128
                                         + ((dh*64 + g*16) ^ swz));
    __builtin_amdgcn_s_setprio(1);
    #pragma unroll
    for (int kt = 0; kt < 2; kt++)
      #pragma unroll
      for (int qt = 0; qt < 2; qt++) {
        f32x4 a = mfma16(ka[kt][0], Qf[qt][0], z);
        st[kt][qt] = mfma16(ka[kt][1], Qf[qt][1], a);
      }
    __builtin_amdgcn_s_setprio(0);
    // fixed-shift softmax: p = exp2(s); kappa makes lane's keys g*8+kt*4+r
    #pragma unroll
    for (int kt = 0; kt < 2; kt++)
      #pragma unroll
      for (int qt = 0; qt < 2; qt++)
        #pragma unroll
        for (int r = 0; r < 4; r++) {
          float pv = __builtin_amdgcn_exp2f(st[kt][qt][r]);
          st[kt][qt][r] = pv;
          lp[qt][kt] += pv;
        }
    // V fragments for this wave's key half (shared across qt)
    bf16x8 vf[4];
    #pragma unroll
    for (int dt = 0; dt < 4; dt++)
      vf[dt] = *(const bf16x8*)(Vc + (dt*16 + l15)*128 + ((rho*64 + g*16) ^ swz));
    // PV with in-register P
    __builtin_amdgcn_s_setprio(1);
    #pragma unroll
    for (int qt = 0; qt < 2; qt++) {
      union { u32 u[4]; bf16x8 v; } pf;
      pf.u[0] = pkb(st[0][qt][0], st[0][qt][1]);
      pf.u[1] = pkb(st[0][qt][2], st[0][qt][3]);
      pf.u[2] = pkb(st[1][qt][0], st[1][qt][1]);
      pf.u[3] = pkb(st[1][qt][2], st[1][qt][3]);
      #pragma unroll
      for (int dt = 0; dt < 4; dt++)
        o[dt][qt] = mfma16(vf[dt], pf.v, o[dt][qt]);
    }
    __builtin_amdgcn_s_setprio(0);
    if (t < 31) {
      if (t < 30) { asm volatile("s_waitcnt vmcnt(2)" ::: "memory"); }
      else        { asm volatile("s_waitcnt vmcnt(0)" ::: "memory"); }
      __builtin_amdgcn_s_barrier();
    }
    cur = (cur + 1 == 3) ? 0 : cur + 1;
    pfb = (pfb + 1 == 3) ? 0 : pfb + 1;
  }
#undef STAGE

  // wave-local denominator per qt (sum over this wave's 32 keys for q=l15)
  float ls[2];
  #pragma unroll
  for (int qt = 0; qt < 2; qt++) {
    ls[qt] = lp[qt][0] + lp[qt][1];
    ls[qt] += __shfl_xor(ls[qt], 16);
    ls[qt] += __shfl_xor(ls[qt], 32);
  }
  __syncthreads();   // all waves done with K/V buffers

  // pair merge phase 1: upper (rho=1) writes f32 partials + denominators
  float* lspx = (float*)(smem + 32768);   // [p][qt*16+l15]
  if (rho == 1) {
    #pragma unroll
    for (int dt = 0; dt < 4; dt++)
      #pragma unroll
      for (int qt = 0; qt < 2; qt++) {
        int ql = qt*16 + l15;
        int off = p*8192 + ql*256 + ((dt*64 + g*16) ^ ((ql & 7) << 4));
        *(f32x4*)(smem + off) = o[dt][qt];
      }
    if (g == 0) {
      lspx[p*64 + l15]      = ls[0];
      lspx[p*64 + 16 + l15] = ls[1];
    }
  }
  __syncthreads();
  // phase 2: lower (rho=0) reads ALL partner partials into registers
  float rls[2] = {0.f, 0.f};
  if (rho == 0) {
    #pragma unroll
    for (int qt = 0; qt < 2; qt++)
      rls[qt] = 1.0f / (ls[qt] + lspx[p*64 + qt*16 + l15]);
    #pragma unroll
    for (int dt = 0; dt < 4; dt++)
      #pragma unroll
      for (int qt = 0; qt < 2; qt++) {
        int ql = qt*16 + l15;
        int off = p*8192 + ql*256 + ((dt*64 + g*16) ^ ((ql & 7) << 4));
        o[dt][qt] += *(const f32x4*)(smem + off);
      }
  }
  __syncthreads();   // ALL f32 reads complete before bf16 rows overwrite them
  // phase 3: lower waves write normalized bf16 rows [q32][128B]
  if (rho == 0) {
    #pragma unroll
    for (int dt = 0; dt < 4; dt++)
      #pragma unroll
      for (int qt = 0; qt < 2; qt++) {
        int ql = qt*16 + l15;
        u32 w0 = pkb(o[dt][qt][0]*rls[qt], o[dt][qt][1]*rls[qt]);
        u32 w1 = pkb(o[dt][qt][2]*rls[qt], o[dt][qt][3]*rls[qt]);
        int d2 = dt*32 + g*8;   // byte offset of d run (d = dt*16+g*4)
        *(uint2*)(smem + p*8192 + ql*128 + (d2 ^ ((ql & 7) << 4))) =
            make_uint2(w0, w1);
      }
  }
  __syncthreads();
  // output: 128 rows x 128B, 512 threads x 2 uint4
  int row = tid >> 2;
  int b = bh >> 4, h = bh & 15;
  int n = qb*128 + row;
  #pragma unroll
  for (int j = 0; j < 2; j++) {
    int slot = (tid & 3)*2 + j;
    uint4 rv = *(const uint4*)(smem + (row >> 5)*8192 + (row & 31)*128
                               + ((slot*16) ^ ((row & 7) << 4)));
    *(uint4*)(aout + ((size_t)(b*2048 + n))*1024 + h*64 + slot*8) = rv;
  }
}

extern "C" void kernel_launch(void* const* d_in, const int* in_sizes, int n_in,
                              void* d_out, int out_size, void* d_ws, size_t ws_size,
                              hipStream_t stream) {
  const float* x    = (const float*)d_in[0];
  const float* lw   = (const float*)d_in[1];
  const float* lb   = (const float*)d_in[2];
  const float* wqkv = (const float*)d_in[3];
  const float* wout = (const float*)d_in[4];
  const float* bout = (const float*)d_in[5];
  float* out = (float*)d_out;

  char* ws = (char*)d_ws;
  size_t off = 0;
  auto alloc = [&](size_t bytes) {
    char* p = ws + off;
    off += (bytes + 255) & ~(size_t)255;
    return p;
  };
  u16* xn   = (u16*)alloc((size_t)ROWS_*DIM_*2);
  u16* wqt  = (u16*)alloc((size_t)3072*1024*2);
  u16* wot  = (u16*)alloc((size_t)1024*1024*2);
  u16* qb   = (u16*)alloc((size_t)BH_*2048*64*2);
  u16* kb   = (u16*)alloc((size_t)BH_*2048*64*2);
  u16* vtb  = (u16*)alloc((size_t)BH_*2048*64*2);
  u16* aout = (u16*)alloc((size_t)ROWS_*1024*2);

  ln_kernel<<<ROWS_, 256, 0, stream>>>(x, lw, lb, xn);
  transpose_f32_bf16<<<dim3(96, 32), 256, 0, stream>>>(wqkv, wqt, 1024, 3072);
  transpose_f32_bf16<<<dim3(32, 32), 256, 0, stream>>>(wout, wot, 1024, 1024);
  gemm256_qkv<<<192, 512, 0, stream>>>(xn, wqt, qb, kb, vtb);
  rope_kernel<<<2048, 256, 0, stream>>>(qb, kb);
  flash_attn<<<512, 512, 0, stream>>>(qb, kb, vtb, aout);
  gemm_bt<1><<<dim3(32, 8), 256, 0, stream>>>(aout, wot, 1024, 1024,
                                              nullptr, nullptr, nullptr, bout, out);
}

// Round 15
// 138.225 us; speedup vs baseline: 1.0134x; 1.0134x over previous
//
#include <hip/hip_runtime.h>

typedef unsigned short u16;
typedef unsigned int   u32;
typedef __bf16 bf16x8 __attribute__((ext_vector_type(8)));
typedef __bf16 bf16x2 __attribute__((ext_vector_type(2)));
typedef float  f32x4  __attribute__((ext_vector_type(4)));

#define B_     2
#define N_     2048
#define DIM_   1024
#define HEADS_ 16
#define DH_    64
#define BH_    (B_*HEADS_)   // 32
#define ROWS_  (B_*N_)       // 4096

__device__ __forceinline__ u16 f2b(float f) {
  union { __bf16 h; u16 u; } v; v.h = (__bf16)f; return v.u;
}
__device__ __forceinline__ u32 pkb(float a, float b) {
  bf16x2 t; t[0] = (__bf16)a; t[1] = (__bf16)b;
  union { bf16x2 v; u32 u; } c; c.v = t; return c.u;
}
__device__ __forceinline__ float b2f(u16 h) {
  union { u32 u; float f; } v; v.u = ((u32)h) << 16;
  return v.f;
}
__device__ __forceinline__ void gload16(const void* g, void* l) {
  __builtin_amdgcn_global_load_lds(
      (const __attribute__((address_space(1))) void*)g,
      (__attribute__((address_space(3))) void*)l, 16, 0, 0);
}
__device__ __forceinline__ f32x4 mfma16(bf16x8 a, bf16x8 b, f32x4 c) {
  return __builtin_amdgcn_mfma_f32_16x16x32_bf16(a, b, c, 0, 0, 0);
}

// ---------------- prep: LN + weight transposes + RoPE tables (one launch) ---
// blocks [0,4096): LayerNorm row        [4096,7168): wqkv^T (96x32)
// [7168,8192): wout^T (32x32)           [8192,8448): cos/sin tables
__global__ __launch_bounds__(256) void prep_kernel(
    const float* __restrict__ x, const float* __restrict__ lw,
    const float* __restrict__ lb, const float* __restrict__ wqkv,
    const float* __restrict__ wout, u16* __restrict__ xn,
    u16* __restrict__ wqt, u16* __restrict__ wot,
    float* __restrict__ cosT, float* __restrict__ sinT) {
  __shared__ float tile[32][33];
  int blk = blockIdx.x, t = threadIdx.x;
  if (blk < 4096) {
    int r = blk;
    const float4* xr = (const float4*)(x + (size_t)r * DIM_);
    float4 v = xr[t];
    float s  = v.x + v.y + v.z + v.w;
    float s2 = v.x*v.x + v.y*v.y + v.z*v.z + v.w*v.w;
    #pragma unroll
    for (int off = 32; off >= 1; off >>= 1) {
      s  += __shfl_down(s, off);
      s2 += __shfl_down(s2, off);
    }
    int w = t >> 6, lane = t & 63;
    if (lane == 0) { tile[0][w] = s; tile[1][w] = s2; }
    __syncthreads();
    if (t == 0) {
      float S = tile[0][0]+tile[0][1]+tile[0][2]+tile[0][3];
      float S2 = tile[1][0]+tile[1][1]+tile[1][2]+tile[1][3];
      float mu = S * (1.0f/DIM_);
      float var = S2 * (1.0f/DIM_) - mu*mu;
      tile[2][0] = mu; tile[2][1] = rsqrtf(var + 1e-5f);
    }
    __syncthreads();
    float mu = tile[2][0], rs = tile[2][1];
    float4 wv = ((const float4*)lw)[t];
    float4 bv = ((const float4*)lb)[t];
    u32 lo = pkb((v.x-mu)*rs*wv.x + bv.x, (v.y-mu)*rs*wv.y + bv.y);
    u32 hi = pkb((v.z-mu)*rs*wv.z + bv.z, (v.w-mu)*rs*wv.w + bv.w);
    ((uint2*)xn)[(size_t)r*256 + t] = make_uint2(lo, hi);
  } else if (blk < 8192) {
    const float* in; u16* outp; int R, C, c0, r0;
    if (blk < 7168) {
      int b2 = blk - 4096;
      in = wqkv; outp = wqt; R = 1024; C = 3072;
      c0 = (b2 % 96) * 32; r0 = (b2 / 96) * 32;
    } else {
      int b2 = blk - 7168;
      in = wout; outp = wot; R = 1024; C = 1024;
      c0 = (b2 & 31) * 32; r0 = (b2 >> 5) * 32;
    }
    int tx = t & 31, ty = t >> 5;
    #pragma unroll
    for (int i = 0; i < 4; i++)
      tile[ty + i*8][tx] = in[(size_t)(r0 + ty + i*8) * C + c0 + tx];
    __syncthreads();
    #pragma unroll
    for (int i = 0; i < 4; i++)
      outp[(size_t)(c0 + ty + i*8) * R + r0 + tx] = f2b(tile[tx][ty + i*8]);
  } else {
    int tid = (blk - 8192) * 256 + t;   // 65536 = 2048*32
    int n = tid >> 5, p = tid & 31;
    float freq = expf(-(2.0f * (float)p) * (9.210340371976184f / 64.0f));
    float ang = (float)n * freq;
    cosT[tid] = cosf(ang);
    sinT[tid] = sinf(ang);
  }
}

// ---------------- QKV GEMM (R13-measured structure) + fused RoPE ----------
// 128x128 tile, BK=32, single-buffer LDS + syncthreads, 2-D grid.
// Epilogue: interleaved RoPE on q/k (partner via shfl_xor(val,1), cos/sin
// from tables); q pre-scaled by DH^-1/2*log2(e); scatter q,k (bh,n,d),
// v^T (bh,d,n).
__global__ __launch_bounds__(256) void gemm_qkv(
    const u16* __restrict__ A, const u16* __restrict__ Bt,
    const float* __restrict__ cosT, const float* __restrict__ sinT,
    u16* __restrict__ qo, u16* __restrict__ ko, u16* __restrict__ vo) {
  const int K = 1024;
  __shared__ __align__(16) u16 lA[128*32];
  __shared__ __align__(16) u16 lB[128*32];
  int tid = threadIdx.x;
  int lane = tid & 63;
  int w = tid >> 6, wm = w >> 1, wn = w & 1;
  int l15 = lane & 15, g = lane >> 4;
  int bm = blockIdx.x, bn = blockIdx.y;
  const f32x4 z = {0.f, 0.f, 0.f, 0.f};
  f32x4 acc[4][4];
  #pragma unroll
  for (int i = 0; i < 4; i++)
    #pragma unroll
    for (int j = 0; j < 4; j++)
      acc[i][j] = z;
  const u16* ag = A  + (size_t)(bm*128 + (tid>>2)) * K + (tid&3)*8;
  const u16* bg = Bt + (size_t)(bn*128 + (tid>>2)) * K + (tid&3)*8;
  u16* la = lA + tid*8;
  u16* lb = lB + tid*8;
  for (int k0 = 0; k0 < K; k0 += 32) {
    gload16(ag + k0,                la);
    gload16(ag + (size_t)64*K + k0, la + 2048);
    gload16(bg + k0,                lb);
    gload16(bg + (size_t)64*K + k0, lb + 2048);
    __syncthreads();
    bf16x8 af[4], bfr[4];
    #pragma unroll
    for (int mt = 0; mt < 4; mt++)
      af[mt] = *(const bf16x8*)(lA + (wm*64 + mt*16 + l15)*32 + g*8);
    #pragma unroll
    for (int nt = 0; nt < 4; nt++)
      bfr[nt] = *(const bf16x8*)(lB + (wn*64 + nt*16 + l15)*32 + g*8);
    __builtin_amdgcn_s_setprio(1);
    #pragma unroll
    for (int mt = 0; mt < 4; mt++)
      #pragma unroll
      for (int nt = 0; nt < 4; nt++)
        acc[mt][nt] = mfma16(af[mt], bfr[nt], acc[mt][nt]);
    __builtin_amdgcn_s_setprio(0);
    __syncthreads();
  }
  const float qs = 0.125f * 1.4426950408889634f;  // DH^-1/2 * log2(e)
  #pragma unroll
  for (int mt = 0; mt < 4; mt++) {
    #pragma unroll
    for (int nt = 0; nt < 4; nt++) {
      #pragma unroll
      for (int reg = 0; reg < 4; reg++) {
        int rr = bm*128 + wm*64 + mt*16 + g*4 + reg;
        int cc = bn*128 + wn*64 + nt*16 + l15;
        float val = acc[mt][nt][reg];
        int which = cc >> 10, inner = cc & 1023;
        int h = inner >> 6, dd = inner & 63;
        int b = rr >> 11, np = rr & 2047;
        int bh = b*HEADS_ + h;
        if (which < 2) {
          // fused interleaved RoPE: partner element sits in lane l15^1
          float pv = __shfl_xor(val, 1);
          int p = dd >> 1;
          float c = cosT[np*32 + p];
          float s = sinT[np*32 + p];
          val = (dd & 1) ? (val*c + pv*s) : (val*c - pv*s);
          if (which == 0) val *= qs;
        }
        if (which == 0)      qo[((size_t)(bh*2048 + np))*64 + dd] = f2b(val);
        else if (which == 1) ko[((size_t)(bh*2048 + np))*64 + dd] = f2b(val);
        else                 vo[((size_t)(bh*64 + dd))*2048 + np] = f2b(val);
      }
    }
  }
}

// ---------------- Output GEMM: 128x64 tile (2 blocks/CU), bias epilogue ----
__global__ __launch_bounds__(256) void gemm_out(
    const u16* __restrict__ A, const u16* __restrict__ Bt,
    const float* __restrict__ bias, float* __restrict__ out) {
  const int K = 1024, N = 1024;
  __shared__ __align__(16) u16 lA[128*32];   // 8KB
  __shared__ __align__(16) u16 lB[64*32];    // 4KB
  int tid = threadIdx.x;
  int lane = tid & 63;
  int w = tid >> 6, wm = w >> 1, wn = w & 1;
  int l15 = lane & 15, g = lane >> 4;
  int bm = blockIdx.x, bn = blockIdx.y;
  const f32x4 z = {0.f, 0.f, 0.f, 0.f};
  f32x4 acc[4][2];
  #pragma unroll
  for (int i = 0; i < 4; i++)
    #pragma unroll
    for (int j = 0; j < 2; j++)
      acc[i][j] = z;
  const u16* ag = A  + (size_t)(bm*128 + (tid>>2)) * K + (tid&3)*8;
  const u16* bg = Bt + (size_t)(bn*64 + (tid>>2)) * K + (tid&2)*8;  // 4 th/row? no:
  // B tile: 64 rows x 32 k = 2048 elems; 256 threads x 8 = 2048.
  // row = tid>>2 covers 0..63 with 4 threads/row x 8 elems = 32 k. (tid&3)*8.
  bg = Bt + (size_t)(bn*64 + (tid>>2)) * K + (tid&3)*8;
  u16* la = lA + tid*8;
  u16* lb = lB + tid*8;
  for (int k0 = 0; k0 < K; k0 += 32) {
    gload16(ag + k0,                la);
    gload16(ag + (size_t)64*K + k0, la + 2048);
    if (tid < 256) gload16(bg + k0, lb);
    __syncthreads();
    bf16x8 af[4], bfr[2];
    #pragma unroll
    for (int mt = 0; mt < 4; mt++)
      af[mt] = *(const bf16x8*)(lA + (wm*64 + mt*16 + l15)*32 + g*8);
    #pragma unroll
    for (int nt = 0; nt < 2; nt++)
      bfr[nt] = *(const bf16x8*)(lB + (wn*32 + nt*16 + l15)*32 + g*8);
    __builtin_amdgcn_s_setprio(1);
    #pragma unroll
    for (int mt = 0; mt < 4; mt++)
      #pragma unroll
      for (int nt = 0; nt < 2; nt++)
        acc[mt][nt] = mfma16(af[mt], bfr[nt], acc[mt][nt]);
    __builtin_amdgcn_s_setprio(0);
    __syncthreads();
  }
  #pragma unroll
  for (int mt = 0; mt < 4; mt++)
    #pragma unroll
    for (int nt = 0; nt < 2; nt++)
      #pragma unroll
      for (int reg = 0; reg < 4; reg++) {
        int rr = bm*128 + wm*64 + mt*16 + g*4 + reg;
        int cc = bn*64 + wn*32 + nt*16 + l15;
        out[(size_t)rr * N + cc] = acc[mt][nt][reg] + bias[cc];
      }
}

// ---------------- Flash attention (key-split wave pairs; R13, measured) -----
__global__ __launch_bounds__(512, 4) void flash_attn(
    const u16* __restrict__ qbf, const u16* __restrict__ kbf,
    const u16* __restrict__ vt, u16* __restrict__ aout) {
  __shared__ __align__(16) char smem[49152];      // 3x8KB K | 3x8KB V; reused
  char* lK = smem;            // lK[buf] at buf*8192
  char* lV = smem + 24576;    // lV[buf] at 24576 + buf*8192
  int tid = threadIdx.x;
  int w = tid >> 6, lane = tid & 63;
  int l15 = lane & 15, g = lane >> 4;
  int p = w & 3, rho = w >> 2;
  int lin = blockIdx.x;
  int nb = (lin & 7) * 64 + (lin >> 3);
  int bh = nb >> 4, qb = nb & 15;
  const f32x4 z = {0.f, 0.f, 0.f, 0.f};
  // Q B-fragments: q = p*32 + qt*16 + l15, d = dh*32 + g*8 .. +7
  const u16* qrow_base = qbf + ((size_t)bh*2048 + qb*128 + p*32) * 64;
  bf16x8 Qf[2][2];
  #pragma unroll
  for (int qt = 0; qt < 2; qt++)
    #pragma unroll
    for (int dh = 0; dh < 2; dh++)
      Qf[qt][dh] = *(const bf16x8*)(qrow_base + (qt*16 + l15)*64 + dh*32 + g*8);
  const char* kb = (const char*)(kbf + (size_t)bh * 2048 * 64);
  const char* vb = (const char*)(vt  + (size_t)bh * 64 * 2048);
  int srow = tid >> 3;                 // LDS row 0..63
  int soff = ((tid & 7) * 16) ^ ((srow & 7) << 4);   // inverse-swizzled source
  // 5-bit kappa within each 32-key half: key = half | (s3s2)<<3 | s4<<2 | s1s0
  int sl = srow & 31;
  int ksrc = (srow & 32) | (((sl >> 2) & 3) << 3) | (((sl >> 4) & 1) << 2) | (sl & 3);
  const int swz = (l15 & 7) << 4;      // row-XOR read swizzle

  float lp[2][2] = {{0.f, 0.f}, {0.f, 0.f}};   // [qt][kt] partial denominators
  f32x4 o[4][2];                               // [dt][qt] partial O^T
  #pragma unroll
  for (int i = 0; i < 4; i++)
    #pragma unroll
    for (int j = 0; j < 2; j++)
      o[i][j] = z;

#define STAGE(t, buf) { \
    gload16(kb + (size_t)((t)*64 + ksrc) * 128 + soff, lK + (buf)*8192 + (size_t)tid*16); \
    gload16(vb + (size_t)srow * 4096 + (t)*128 + soff, lV + (buf)*8192 + (size_t)tid*16); }

  STAGE(0, 0)
  STAGE(1, 1)
  asm volatile("s_waitcnt vmcnt(2)" ::: "memory");
  __builtin_amdgcn_s_barrier();

  int cur = 0, pfb = 2;
  #pragma unroll 1
  for (int t = 0; t < 32; ++t) {
    if (t < 30) STAGE(t + 2, pfb)
    const char* Kc = lK + cur*8192;
    const char* Vc = lV + cur*8192;
    // QK^T over this wave's 32-key half: st[kt][qt]
    f32x4 st[2][2];
    bf16x8 ka[2][2];
    #pragma unroll
    for (int kt = 0; kt < 2; kt++)
      #pragma unroll
      for (int dh = 0; dh < 2; dh++)
        ka[kt][dh] = *(const bf16x8*)(Kc + (rho*32 + kt*16 + l15)*128
                                         + ((dh*64 + g*16) ^ swz));
    __builtin_amdgcn_s_setprio(1);
    #pragma unroll
    for (int kt = 0; kt < 2; kt++)
      #pragma unroll
      for (int qt = 0; qt < 2; qt++) {
        f32x4 a = mfma16(ka[kt][0], Qf[qt][0], z);
        st[kt][qt] = mfma16(ka[kt][1], Qf[qt][1], a);
      }
    __builtin_amdgcn_s_setprio(0);
    // fixed-shift softmax: p = exp2(s); kappa makes lane's keys g*8+kt*4+r
    #pragma unroll
    for (int kt = 0; kt < 2; kt++)
      #pragma unroll
      for (int qt = 0; qt < 2; qt++)
        #pragma unroll
        for (int r = 0; r < 4; r++) {
          float pv = __builtin_amdgcn_exp2f(st[kt][qt][r]);
          st[kt][qt][r] = pv;
          lp[qt][kt] += pv;
        }
    // V fragments for this wave's key half (shared across qt)
    bf16x8 vf[4];
    #pragma unroll
    for (int dt = 0; dt < 4; dt++)
      vf[dt] = *(const bf16x8*)(Vc + (dt*16 + l15)*128 + ((rho*64 + g*16) ^ swz));
    // PV with in-register P
    __builtin_amdgcn_s_setprio(1);
    #pragma unroll
    for (int qt = 0; qt < 2; qt++) {
      union { u32 u[4]; bf16x8 v; } pf;
      pf.u[0] = pkb(st[0][qt][0], st[0][qt][1]);
      pf.u[1] = pkb(st[0][qt][2], st[0][qt][3]);
      pf.u[2] = pkb(st[1][qt][0], st[1][qt][1]);
      pf.u[3] = pkb(st[1][qt][2], st[1][qt][3]);
      #pragma unroll
      for (int dt = 0; dt < 4; dt++)
        o[dt][qt] = mfma16(vf[dt], pf.v, o[dt][qt]);
    }
    __builtin_amdgcn_s_setprio(0);
    if (t < 31) {
      if (t < 30) { asm volatile("s_waitcnt vmcnt(2)" ::: "memory"); }
      else        { asm volatile("s_waitcnt vmcnt(0)" ::: "memory"); }
      __builtin_amdgcn_s_barrier();
    }
    cur = (cur + 1 == 3) ? 0 : cur + 1;
    pfb = (pfb + 1 == 3) ? 0 : pfb + 1;
  }
#undef STAGE

  // wave-local denominator per qt (sum over this wave's 32 keys for q=l15)
  float ls[2];
  #pragma unroll
  for (int qt = 0; qt < 2; qt++) {
    ls[qt] = lp[qt][0] + lp[qt][1];
    ls[qt] += __shfl_xor(ls[qt], 16);
    ls[qt] += __shfl_xor(ls[qt], 32);
  }
  __syncthreads();   // all waves done with K/V buffers

  // pair merge phase 1: upper (rho=1) writes f32 partials + denominators
  float* lspx = (float*)(smem + 32768);   // [p][qt*16+l15]
  if (rho == 1) {
    #pragma unroll
    for (int dt = 0; dt < 4; dt++)
      #pragma unroll
      for (int qt = 0; qt < 2; qt++) {
        int ql = qt*16 + l15;
        int off = p*8192 + ql*256 + ((dt*64 + g*16) ^ ((ql & 7) << 4));
        *(f32x4*)(smem + off) = o[dt][qt];
      }
    if (g == 0) {
      lspx[p*64 + l15]      = ls[0];
      lspx[p*64 + 16 + l15] = ls[1];
    }
  }
  __syncthreads();
  // phase 2: lower (rho=0) reads ALL partner partials into registers
  float rls[2] = {0.f, 0.f};
  if (rho == 0) {
    #pragma unroll
    for (int qt = 0; qt < 2; qt++)
      rls[qt] = 1.0f / (ls[qt] + lspx[p*64 + qt*16 + l15]);
    #pragma unroll
    for (int dt = 0; dt < 4; dt++)
      #pragma unroll
      for (int qt = 0; qt < 2; qt++) {
        int ql = qt*16 + l15;
        int off = p*8192 + ql*256 + ((dt*64 + g*16) ^ ((ql & 7) << 4));
        o[dt][qt] += *(const f32x4*)(smem + off);
      }
  }
  __syncthreads();   // ALL f32 reads complete before bf16 rows overwrite them
  // phase 3: lower waves write normalized bf16 rows [q32][128B]
  if (rho == 0) {
    #pragma unroll
    for (int dt = 0; dt < 4; dt++)
      #pragma unroll
      for (int qt = 0; qt < 2; qt++) {
        int ql = qt*16 + l15;
        u32 w0 = pkb(o[dt][qt][0]*rls[qt], o[dt][qt][1]*rls[qt]);
        u32 w1 = pkb(o[dt][qt][2]*rls[qt], o[dt][qt][3]*rls[qt]);
        int d2 = dt*32 + g*8;   // byte offset of d run (d = dt*16+g*4)
        *(uint2*)(smem + p*8192 + ql*128 + (d2 ^ ((ql & 7) << 4))) =
            make_uint2(w0, w1);
      }
  }
  __syncthreads();
  // output: 128 rows x 128B, 512 threads x 2 uint4
  int row = tid >> 2;
  int b = bh >> 4, h = bh & 15;
  int n = qb*128 + row;
  #pragma unroll
  for (int j = 0; j < 2; j++) {
    int slot = (tid & 3)*2 + j;
    uint4 rv = *(const uint4*)(smem + (row >> 5)*8192 + (row & 31)*128
                               + ((slot*16) ^ ((row & 7) << 4)));
    *(uint4*)(aout + ((size_t)(b*2048 + n))*1024 + h*64 + slot*8) = rv;
  }
}

extern "C" void kernel_launch(void* const* d_in, const int* in_sizes, int n_in,
                              void* d_out, int out_size, void* d_ws, size_t ws_size,
                              hipStream_t stream) {
  const float* x    = (const float*)d_in[0];
  const float* lw   = (const float*)d_in[1];
  const float* lb   = (const float*)d_in[2];
  const float* wqkv = (const float*)d_in[3];
  const float* wout = (const float*)d_in[4];
  const float* bout = (const float*)d_in[5];
  float* out = (float*)d_out;

  char* ws = (char*)d_ws;
  size_t off = 0;
  auto alloc = [&](size_t bytes) {
    char* p = ws + off;
    off += (bytes + 255) & ~(size_t)255;
    return p;
  };
  u16* xn   = (u16*)alloc((size_t)ROWS_*DIM_*2);
  u16* wqt  = (u16*)alloc((size_t)3072*1024*2);
  u16* wot  = (u16*)alloc((size_t)1024*1024*2);
  u16* qb   = (u16*)alloc((size_t)BH_*2048*64*2);
  u16* kb   = (u16*)alloc((size_t)BH_*2048*64*2);
  u16* vtb  = (u16*)alloc((size_t)BH_*2048*64*2);
  u16* aout = (u16*)alloc((size_t)ROWS_*1024*2);
  float* cosT = (float*)alloc((size_t)2048*32*4);
  float* sinT = (float*)alloc((size_t)2048*32*4);

  prep_kernel<<<8448, 256, 0, stream>>>(x, lw, lb, wqkv, wout,
                                        xn, wqt, wot, cosT, sinT);
  gemm_qkv<<<dim3(32, 24), 256, 0, stream>>>(xn, wqt, cosT, sinT,
                                             qb, kb, vtb);
  flash_attn<<<512, 512, 0, stream>>>(qb, kb, vtb, aout);
  gemm_out<<<dim3(32, 16), 256, 0, stream>>>(aout, wot, bout, out);
}

// Round 16
// 116.951 us; speedup vs baseline: 1.1977x; 1.1819x over previous
//
#include <hip/hip_runtime.h>

typedef unsigned short u16;
typedef unsigned int   u32;
typedef __bf16 bf16x8 __attribute__((ext_vector_type(8)));
typedef __bf16 bf16x2 __attribute__((ext_vector_type(2)));
typedef float  f32x4  __attribute__((ext_vector_type(4)));

#define B_     2
#define N_     2048
#define DIM_   1024
#define HEADS_ 16
#define DH_    64
#define BH_    (B_*HEADS_)   // 32
#define ROWS_  (B_*N_)       // 4096

__device__ __forceinline__ u16 f2b(float f) {
  union { __bf16 h; u16 u; } v; v.h = (__bf16)f; return v.u;
}
__device__ __forceinline__ u32 pkb(float a, float b) {
  bf16x2 t; t[0] = (__bf16)a; t[1] = (__bf16)b;
  union { bf16x2 v; u32 u; } c; c.v = t; return c.u;
}
__device__ __forceinline__ float b2f(u16 h) {
  union { u32 u; float f; } v; v.u = ((u32)h) << 16;
  return v.f;
}
__device__ __forceinline__ void gload16(const void* g, void* l) {
  __builtin_amdgcn_global_load_lds(
      (const __attribute__((address_space(1))) void*)g,
      (__attribute__((address_space(3))) void*)l, 16, 0, 0);
}
__device__ __forceinline__ f32x4 mfma16(bf16x8 a, bf16x8 b, f32x4 c) {
  return __builtin_amdgcn_mfma_f32_16x16x32_bf16(a, b, c, 0, 0, 0);
}

// ---------------- prep: LN + weight transposes (one launch) ----------------
// blocks [0,4096): LayerNorm row   [4096,7168): wqkv^T   [7168,8192): wout^T
__global__ __launch_bounds__(256) void prep_kernel(
    const float* __restrict__ x, const float* __restrict__ lw,
    const float* __restrict__ lb, const float* __restrict__ wqkv,
    const float* __restrict__ wout, u16* __restrict__ xn,
    u16* __restrict__ wqt, u16* __restrict__ wot) {
  __shared__ float tile[32][33];
  int blk = blockIdx.x, t = threadIdx.x;
  if (blk < 4096) {
    int r = blk;
    const float4* xr = (const float4*)(x + (size_t)r * DIM_);
    float4 v = xr[t];
    float s  = v.x + v.y + v.z + v.w;
    float s2 = v.x*v.x + v.y*v.y + v.z*v.z + v.w*v.w;
    #pragma unroll
    for (int off = 32; off >= 1; off >>= 1) {
      s  += __shfl_down(s, off);
      s2 += __shfl_down(s2, off);
    }
    int w = t >> 6, lane = t & 63;
    if (lane == 0) { tile[0][w] = s; tile[1][w] = s2; }
    __syncthreads();
    if (t == 0) {
      float S = tile[0][0]+tile[0][1]+tile[0][2]+tile[0][3];
      float S2 = tile[1][0]+tile[1][1]+tile[1][2]+tile[1][3];
      float mu = S * (1.0f/DIM_);
      float var = S2 * (1.0f/DIM_) - mu*mu;
      tile[2][0] = mu; tile[2][1] = rsqrtf(var + 1e-5f);
    }
    __syncthreads();
    float mu = tile[2][0], rs = tile[2][1];
    float4 wv = ((const float4*)lw)[t];
    float4 bv = ((const float4*)lb)[t];
    u32 lo = pkb((v.x-mu)*rs*wv.x + bv.x, (v.y-mu)*rs*wv.y + bv.y);
    u32 hi = pkb((v.z-mu)*rs*wv.z + bv.z, (v.w-mu)*rs*wv.w + bv.w);
    ((uint2*)xn)[(size_t)r*256 + t] = make_uint2(lo, hi);
  } else {
    const float* in; u16* outp; int R, C, c0, r0;
    if (blk < 7168) {
      int b2 = blk - 4096;
      in = wqkv; outp = wqt; R = 1024; C = 3072;
      c0 = (b2 % 96) * 32; r0 = (b2 / 96) * 32;
    } else {
      int b2 = blk - 7168;
      in = wout; outp = wot; R = 1024; C = 1024;
      c0 = (b2 & 31) * 32; r0 = (b2 >> 5) * 32;
    }
    int tx = t & 31, ty = t >> 5;
    #pragma unroll
    for (int i = 0; i < 4; i++)
      tile[ty + i*8][tx] = in[(size_t)(r0 + ty + i*8) * C + c0 + tx];
    __syncthreads();
    #pragma unroll
    for (int i = 0; i < 4; i++)
      outp[(size_t)(c0 + ty + i*8) * R + r0 + tx] = f2b(tile[tx][ty + i*8]);
  }
}

// ---------------- QKV GEMM (R13-measured best, unchanged) ------------------
// 128x128 tile, BK=32, single-buffer LDS + syncthreads, 2-D grid.
// Scatter epilogue: q (bh,n,d), k (bh,n,d), v^T (bh,d,n).
__global__ __launch_bounds__(256) void gemm_qkv(
    const u16* __restrict__ A, const u16* __restrict__ Bt,
    u16* __restrict__ qo, u16* __restrict__ ko, u16* __restrict__ vo) {
  const int K = 1024;
  __shared__ __align__(16) u16 lA[128*32];
  __shared__ __align__(16) u16 lB[128*32];
  int tid = threadIdx.x;
  int lane = tid & 63;
  int w = tid >> 6, wm = w >> 1, wn = w & 1;
  int l15 = lane & 15, g = lane >> 4;
  int bm = blockIdx.x, bn = blockIdx.y;
  const f32x4 z = {0.f, 0.f, 0.f, 0.f};
  f32x4 acc[4][4];
  #pragma unroll
  for (int i = 0; i < 4; i++)
    #pragma unroll
    for (int j = 0; j < 4; j++)
      acc[i][j] = z;
  const u16* ag = A  + (size_t)(bm*128 + (tid>>2)) * K + (tid&3)*8;
  const u16* bg = Bt + (size_t)(bn*128 + (tid>>2)) * K + (tid&3)*8;
  u16* la = lA + tid*8;
  u16* lb = lB + tid*8;
  for (int k0 = 0; k0 < K; k0 += 32) {
    gload16(ag + k0,                la);
    gload16(ag + (size_t)64*K + k0, la + 2048);
    gload16(bg + k0,                lb);
    gload16(bg + (size_t)64*K + k0, lb + 2048);
    __syncthreads();
    bf16x8 af[4], bfr[4];
    #pragma unroll
    for (int mt = 0; mt < 4; mt++)
      af[mt] = *(const bf16x8*)(lA + (wm*64 + mt*16 + l15)*32 + g*8);
    #pragma unroll
    for (int nt = 0; nt < 4; nt++)
      bfr[nt] = *(const bf16x8*)(lB + (wn*64 + nt*16 + l15)*32 + g*8);
    __builtin_amdgcn_s_setprio(1);
    #pragma unroll
    for (int mt = 0; mt < 4; mt++)
      #pragma unroll
      for (int nt = 0; nt < 4; nt++)
        acc[mt][nt] = mfma16(af[mt], bfr[nt], acc[mt][nt]);
    __builtin_amdgcn_s_setprio(0);
    __syncthreads();
  }
  #pragma unroll
  for (int mt = 0; mt < 4; mt++) {
    #pragma unroll
    for (int nt = 0; nt < 4; nt++) {
      #pragma unroll
      for (int reg = 0; reg < 4; reg++) {
        int rr = bm*128 + wm*64 + mt*16 + g*4 + reg;
        int cc = bn*128 + wn*64 + nt*16 + l15;
        float val = acc[mt][nt][reg];
        int which = cc >> 10, inner = cc & 1023;
        int h = inner >> 6, dd = inner & 63;
        int b = rr >> 11, np = rr & 2047;
        int bh = b*HEADS_ + h;
        if (which == 0)      qo[((size_t)(bh*2048 + np))*64 + dd] = f2b(val);
        else if (which == 1) ko[((size_t)(bh*2048 + np))*64 + dd] = f2b(val);
        else                 vo[((size_t)(bh*64 + dd))*2048 + np] = f2b(val);
      }
    }
  }
}

// ---------------- RoPE in-place on q,k (bh,n,64); coalesced, inline trig ----
// q additionally scaled by DH^-1/2 * log2(e)  (scores land in log2 domain)
__global__ __launch_bounds__(256) void rope_kernel(u16* q, u16* k) {
  int tid = blockIdx.x * 256 + threadIdx.x;   // 524288 = BH*N*8
  int row = tid >> 3, sub = tid & 7;
  int n = row & 2047;
  u32* qp = (u32*)(q + (size_t)row * 64 + sub * 8);
  u32* kp = (u32*)(k + (size_t)row * 64 + sub * 8);
  uint4 uq = *(uint4*)qp;
  uint4 uk = *(uint4*)kp;
  float c4[4], s4[4];
  #pragma unroll
  for (int j = 0; j < 4; j++) {
    int p = sub*4 + j;
    float freq = expf(-(2.0f * (float)p) * (9.210340371976184f / 64.0f));
    float ang = (float)n * freq;
    __sincosf(ang, &s4[j], &c4[j]);
  }
  const float qs = 0.125f * 1.4426950408889634f;
#define ROPE_Q(u, c, s) { \
    float e = b2f((u16)(u)), o = b2f((u16)((u) >> 16)); \
    (u) = pkb((e*(c) - o*(s))*qs, (o*(c) + e*(s))*qs); }
#define ROPE_K(u, c, s) { \
    float e = b2f((u16)(u)), o = b2f((u16)((u) >> 16)); \
    (u) = pkb(e*(c) - o*(s), o*(c) + e*(s)); }
  ROPE_Q(uq.x, c4[0], s4[0]) ROPE_Q(uq.y, c4[1], s4[1])
  ROPE_Q(uq.z, c4[2], s4[2]) ROPE_Q(uq.w, c4[3], s4[3])
  ROPE_K(uk.x, c4[0], s4[0]) ROPE_K(uk.y, c4[1], s4[1])
  ROPE_K(uk.z, c4[2], s4[2]) ROPE_K(uk.w, c4[3], s4[3])
#undef ROPE_Q
#undef ROPE_K
  *(uint4*)qp = uq;
  *(uint4*)kp = uk;
}

// ---------------- Output GEMM: 128x64 tile (2 blocks/CU), bias epilogue ----
__global__ __launch_bounds__(256) void gemm_out(
    const u16* __restrict__ A, const u16* __restrict__ Bt,
    const float* __restrict__ bias, float* __restrict__ out) {
  const int K = 1024, N = 1024;
  __shared__ __align__(16) u16 lA[128*32];   // 8KB
  __shared__ __align__(16) u16 lB[64*32];    // 4KB
  int tid = threadIdx.x;
  int lane = tid & 63;
  int w = tid >> 6, wm = w >> 1, wn = w & 1;
  int l15 = lane & 15, g = lane >> 4;
  int bm = blockIdx.x, bn = blockIdx.y;
  const f32x4 z = {0.f, 0.f, 0.f, 0.f};
  f32x4 acc[4][2];
  #pragma unroll
  for (int i = 0; i < 4; i++)
    #pragma unroll
    for (int j = 0; j < 2; j++)
      acc[i][j] = z;
  const u16* ag = A  + (size_t)(bm*128 + (tid>>2)) * K + (tid&3)*8;
  const u16* bg = Bt + (size_t)(bn*64 + (tid>>2)) * K + (tid&3)*8;
  u16* la = lA + tid*8;
  u16* lb = lB + tid*8;   // only tids 0..255 cover 64 rows x 32 k
  for (int k0 = 0; k0 < K; k0 += 32) {
    gload16(ag + k0,                la);
    gload16(ag + (size_t)64*K + k0, la + 2048);
    gload16(bg + k0,                lb);
    __syncthreads();
    bf16x8 af[4], bfr[2];
    #pragma unroll
    for (int mt = 0; mt < 4; mt++)
      af[mt] = *(const bf16x8*)(lA + (wm*64 + mt*16 + l15)*32 + g*8);
    #pragma unroll
    for (int nt = 0; nt < 2; nt++)
      bfr[nt] = *(const bf16x8*)(lB + (wn*32 + nt*16 + l15)*32 + g*8);
    __builtin_amdgcn_s_setprio(1);
    #pragma unroll
    for (int mt = 0; mt < 4; mt++)
      #pragma unroll
      for (int nt = 0; nt < 2; nt++)
        acc[mt][nt] = mfma16(af[mt], bfr[nt], acc[mt][nt]);
    __builtin_amdgcn_s_setprio(0);
    __syncthreads();
  }
  #pragma unroll
  for (int mt = 0; mt < 4; mt++)
    #pragma unroll
    for (int nt = 0; nt < 2; nt++)
      #pragma unroll
      for (int reg = 0; reg < 4; reg++) {
        int rr = bm*128 + wm*64 + mt*16 + g*4 + reg;
        int cc = bn*64 + wn*32 + nt*16 + l15;
        out[(size_t)rr * N + cc] = acc[mt][nt][reg] + bias[cc];
      }
}

// ---------------- Flash attention (key-split wave pairs; R13, measured) -----
__global__ __launch_bounds__(512, 4) void flash_attn(
    const u16* __restrict__ qbf, const u16* __restrict__ kbf,
    const u16* __restrict__ vt, u16* __restrict__ aout) {
  __shared__ __align__(16) char smem[49152];      // 3x8KB K | 3x8KB V; reused
  char* lK = smem;            // lK[buf] at buf*8192
  char* lV = smem + 24576;    // lV[buf] at 24576 + buf*8192
  int tid = threadIdx.x;
  int w = tid >> 6, lane = tid & 63;
  int l15 = lane & 15, g = lane >> 4;
  int p = w & 3, rho = w >> 2;
  int lin = blockIdx.x;
  int nb = (lin & 7) * 64 + (lin >> 3);
  int bh = nb >> 4, qb = nb & 15;
  const f32x4 z = {0.f, 0.f, 0.f, 0.f};
  // Q B-fragments: q = p*32 + qt*16 + l15, d = dh*32 + g*8 .. +7
  const u16* qrow_base = qbf + ((size_t)bh*2048 + qb*128 + p*32) * 64;
  bf16x8 Qf[2][2];
  #pragma unroll
  for (int qt = 0; qt < 2; qt++)
    #pragma unroll
    for (int dh = 0; dh < 2; dh++)
      Qf[qt][dh] = *(const bf16x8*)(qrow_base + (qt*16 + l15)*64 + dh*32 + g*8);
  const char* kb = (const char*)(kbf + (size_t)bh * 2048 * 64);
  const char* vb = (const char*)(vt  + (size_t)bh * 64 * 2048);
  int srow = tid >> 3;                 // LDS row 0..63
  int soff = ((tid & 7) * 16) ^ ((srow & 7) << 4);   // inverse-swizzled source
  // 5-bit kappa within each 32-key half: key = half | (s3s2)<<3 | s4<<2 | s1s0
  int sl = srow & 31;
  int ksrc = (srow & 32) | (((sl >> 2) & 3) << 3) | (((sl >> 4) & 1) << 2) | (sl & 3);
  const int swz = (l15 & 7) << 4;      // row-XOR read swizzle

  float lp[2][2] = {{0.f, 0.f}, {0.f, 0.f}};   // [qt][kt] partial denominators
  f32x4 o[4][2];                               // [dt][qt] partial O^T
  #pragma unroll
  for (int i = 0; i < 4; i++)
    #pragma unroll
    for (int j = 0; j < 2; j++)
      o[i][j] = z;

#define STAGE(t, buf) { \
    gload16(kb + (size_t)((t)*64 + ksrc) * 128 + soff, lK + (buf)*8192 + (size_t)tid*16); \
    gload16(vb + (size_t)srow * 4096 + (t)*128 + soff, lV + (buf)*8192 + (size_t)tid*16); }

  STAGE(0, 0)
  STAGE(1, 1)
  asm volatile("s_waitcnt vmcnt(2)" ::: "memory");
  __builtin_amdgcn_s_barrier();

  int cur = 0, pfb = 2;
  #pragma unroll 1
  for (int t = 0; t < 32; ++t) {
    if (t < 30) STAGE(t + 2, pfb)
    const char* Kc = lK + cur*8192;
    const char* Vc = lV + cur*8192;
    // QK^T over this wave's 32-key half: st[kt][qt]
    f32x4 st[2][2];
    bf16x8 ka[2][2];
    #pragma unroll
    for (int kt = 0; kt < 2; kt++)
      #pragma unroll
      for (int dh = 0; dh < 2; dh++)
        ka[kt][dh] = *(const bf16x8*)(Kc + (rho*32 + kt*16 + l15)*128
                                         + ((dh*64 + g*16) ^ swz));
    __builtin_amdgcn_s_setprio(1);
    #pragma unroll
    for (int kt = 0; kt < 2; kt++)
      #pragma unroll
      for (int qt = 0; qt < 2; qt++) {
        f32x4 a = mfma16(ka[kt][0], Qf[qt][0], z);
        st[kt][qt] = mfma16(ka[kt][1], Qf[qt][1], a);
      }
    __builtin_amdgcn_s_setprio(0);
    // fixed-shift softmax: p = exp2(s); kappa makes lane's keys g*8+kt*4+r
    #pragma unroll
    for (int kt = 0; kt < 2; kt++)
      #pragma unroll
      for (int qt = 0; qt < 2; qt++)
        #pragma unroll
        for (int r = 0; r < 4; r++) {
          float pv = __builtin_amdgcn_exp2f(st[kt][qt][r]);
          st[kt][qt][r] = pv;
          lp[qt][kt] += pv;
        }
    // V fragments for this wave's key half (shared across qt)
    bf16x8 vf[4];
    #pragma unroll
    for (int dt = 0; dt < 4; dt++)
      vf[dt] = *(const bf16x8*)(Vc + (dt*16 + l15)*128 + ((rho*64 + g*16) ^ swz));
    // PV with in-register P
    __builtin_amdgcn_s_setprio(1);
    #pragma unroll
    for (int qt = 0; qt < 2; qt++) {
      union { u32 u[4]; bf16x8 v; } pf;
      pf.u[0] = pkb(st[0][qt][0], st[0][qt][1]);
      pf.u[1] = pkb(st[0][qt][2], st[0][qt][3]);
      pf.u[2] = pkb(st[1][qt][0], st[1][qt][1]);
      pf.u[3] = pkb(st[1][qt][2], st[1][qt][3]);
      #pragma unroll
      for (int dt = 0; dt < 4; dt++)
        o[dt][qt] = mfma16(vf[dt], pf.v, o[dt][qt]);
    }
    __builtin_amdgcn_s_setprio(0);
    if (t < 31) {
      if (t < 30) { asm volatile("s_waitcnt vmcnt(2)" ::: "memory"); }
      else        { asm volatile("s_waitcnt vmcnt(0)" ::: "memory"); }
      __builtin_amdgcn_s_barrier();
    }
    cur = (cur + 1 == 3) ? 0 : cur + 1;
    pfb = (pfb + 1 == 3) ? 0 : pfb + 1;
  }
#undef STAGE

  // wave-local denominator per qt (sum over this wave's 32 keys for q=l15)
  float ls[2];
  #pragma unroll
  for (int qt = 0; qt < 2; qt++) {
    ls[qt] = lp[qt][0] + lp[qt][1];
    ls[qt] += __shfl_xor(ls[qt], 16);
    ls[qt] += __shfl_xor(ls[qt], 32);
  }
  __syncthreads();   // all waves done with K/V buffers

  // pair merge phase 1: upper (rho=1) writes f32 partials + denominators
  float* lspx = (float*)(smem + 32768);   // [p][qt*16+l15]
  if (rho == 1) {
    #pragma unroll
    for (int dt = 0; dt < 4; dt++)
      #pragma unroll
      for (int qt = 0; qt < 2; qt++) {
        int ql = qt*16 + l15;
        int off = p*8192 + ql*256 + ((dt*64 + g*16) ^ ((ql & 7) << 4));
        *(f32x4*)(smem + off) = o[dt][qt];
      }
    if (g == 0) {
      lspx[p*64 + l15]      = ls[0];
      lspx[p*64 + 16 + l15] = ls[1];
    }
  }
  __syncthreads();
  // phase 2: lower (rho=0) reads ALL partner partials into registers
  float rls[2] = {0.f, 0.f};
  if (rho == 0) {
    #pragma unroll
    for (int qt = 0; qt < 2; qt++)
      rls[qt] = 1.0f / (ls[qt] + lspx[p*64 + qt*16 + l15]);
    #pragma unroll
    for (int dt = 0; dt < 4; dt++)
      #pragma unroll
      for (int qt = 0; qt < 2; qt++) {
        int ql = qt*16 + l15;
        int off = p*8192 + ql*256 + ((dt*64 + g*16) ^ ((ql & 7) << 4));
        o[dt][qt] += *(const f32x4*)(smem + off);
      }
  }
  __syncthreads();   // ALL f32 reads complete before bf16 rows overwrite them
  // phase 3: lower waves write normalized bf16 rows [q32][128B]
  if (rho == 0) {
    #pragma unroll
    for (int dt = 0; dt < 4; dt++)
      #pragma unroll
      for (int qt = 0; qt < 2; qt++) {
        int ql = qt*16 + l15;
        u32 w0 = pkb(o[dt][qt][0]*rls[qt], o[dt][qt][1]*rls[qt]);
        u32 w1 = pkb(o[dt][qt][2]*rls[qt], o[dt][qt][3]*rls[qt]);
        int d2 = dt*32 + g*8;   // byte offset of d run (d = dt*16+g*4)
        *(uint2*)(smem + p*8192 + ql*128 + (d2 ^ ((ql & 7) << 4))) =
            make_uint2(w0, w1);
      }
  }
  __syncthreads();
  // output: 128 rows x 128B, 512 threads x 2 uint4
  int row = tid >> 2;
  int b = bh >> 4, h = bh & 15;
  int n = qb*128 + row;
  #pragma unroll
  for (int j = 0; j < 2; j++) {
    int slot = (tid & 3)*2 + j;
    uint4 rv = *(const uint4*)(smem + (row >> 5)*8192 + (row & 31)*128
                               + ((slot*16) ^ ((row & 7) << 4)));
    *(uint4*)(aout + ((size_t)(b*2048 + n))*1024 + h*64 + slot*8) = rv;
  }
}

extern "C" void kernel_launch(void* const* d_in, const int* in_sizes, int n_in,
                              void* d_out, int out_size, void* d_ws, size_t ws_size,
                              hipStream_t stream) {
  const float* x    = (const float*)d_in[0];
  const float* lw   = (const float*)d_in[1];
  const float* lb   = (const float*)d_in[2];
  const float* wqkv = (const float*)d_in[3];
  const float* wout = (const float*)d_in[4];
  const float* bout = (const float*)d_in[5];
  float* out = (float*)d_out;

  char* ws = (char*)d_ws;
  size_t off = 0;
  auto alloc = [&](size_t bytes) {
    char* p = ws + off;
    off += (bytes + 255) & ~(size_t)255;
    return p;
  };
  u16* xn   = (u16*)alloc((size_t)ROWS_*DIM_*2);
  u16* wqt  = (u16*)alloc((size_t)3072*1024*2);
  u16* wot  = (u16*)alloc((size_t)1024*1024*2);
  u16* qb   = (u16*)alloc((size_t)BH_*2048*64*2);
  u16* kb   = (u16*)alloc((size_t)BH_*2048*64*2);
  u16* vtb  = (u16*)alloc((size_t)BH_*2048*64*2);
  u16* aout = (u16*)alloc((size_t)ROWS_*1024*2);

  prep_kernel<<<8192, 256, 0, stream>>>(x, lw, lb, wqkv, wout, xn, wqt, wot);
  gemm_qkv<<<dim3(32, 24), 256, 0, stream>>>(xn, wqt, qb, kb, vtb);
  rope_kernel<<<2048, 256, 0, stream>>>(qb, kb);
  flash_attn<<<512, 512, 0, stream>>>(qb, kb, vtb, aout);
  gemm_out<<<dim3(32, 16), 256, 0, stream>>>(aout, wot, bout, out);
}